// Round 2
// baseline (3117.516 us; speedup 1.0000x reference)
//
#include <hip/hip_runtime.h>
#include <hip/hip_bf16.h>
#include <stdint.h>

// GCN layer: out = D^-1/2 (A+I) D^-1/2 (x W + b)
// N=100000 nodes, E=3.2M edges, 256 -> 128 features.
// Pipeline: degree count -> rsqrt -> fp32 GEMM (h stored bf16-packed, lane j
// holds feats (j, j+64)) -> bucket partition of edges (64 rows/bucket) ->
// per-bucket LDS-accumulated aggregation (no CSR, no output atomics).

__device__ __forceinline__ float bf_lo(uint32_t p) { return __uint_as_float(p << 16); }
__device__ __forceinline__ float bf_hi(uint32_t p) { return __uint_as_float(p & 0xffff0000u); }

__device__ __forceinline__ uint32_t f2bf(float f) {
  uint32_t u = __float_as_uint(f);
  return (u + 0x7fffu + ((u >> 16) & 1u)) >> 16;  // RNE
}
__device__ __forceinline__ uint32_t pack_bf16(float lo, float hi) {
  return (f2bf(hi) << 16) | f2bf(lo);
}

// ---- degree count ----
__global__ void k_count(const int* __restrict__ rows, int E, int* __restrict__ deg) {
  int e = blockIdx.x * blockDim.x + threadIdx.x;
  if (e < E) atomicAdd(&deg[rows[e]], 1);
}

// ---- d^-1/2 (deg includes +1 self loop) ----
__global__ void k_dis(const int* __restrict__ deg, float* __restrict__ dis, int N) {
  int i = blockIdx.x * blockDim.x + threadIdx.x;
  if (i < N) dis[i] = rsqrtf((float)(deg[i] + 1));
}

// ---- per-bucket edge counts: bcnt[b] = sum deg[64b .. 64b+63] ----
__global__ void k_bucketcnt(const int* __restrict__ deg, int N, int NB,
                            int* __restrict__ bcnt) {
  int b = blockIdx.x * 4 + (threadIdx.x >> 6);
  int lane = threadIdx.x & 63;
  if (b >= NB) return;
  int r = b * 64 + lane;
  int v = (r < N) ? deg[r] : 0;
  for (int d = 32; d; d >>= 1) v += __shfl_down(v, d);
  if (lane == 0) bcnt[b] = v;
}

// ---- exclusive scan of bucket counts (single block, n <= 2048) ----
__global__ void k_scanb(const int* __restrict__ bcnt, int n,
                        int* __restrict__ gbase, int* __restrict__ gcur) {
  __shared__ int s[2048];
  int t = threadIdx.x;  // 1024 threads
  int v0 = (t < n) ? bcnt[t] : 0;
  int v1 = (t + 1024 < n) ? bcnt[t + 1024] : 0;
  s[t] = v0; s[t + 1024] = v1;
  __syncthreads();
  for (int d = 1; d < 2048; d <<= 1) {
    int a0 = (t >= d) ? s[t - d] : 0;
    int a1 = s[t + 1024 - d];  // t+1024 >= d always (d <= 1024)
    __syncthreads();
    s[t] += a0; s[t + 1024] += a1;
    __syncthreads();
  }
  if (t < n)        { int e = s[t] - v0;        gbase[t] = e;        gcur[t] = e; }
  if (t + 1024 < n) { int e = s[t + 1024] - v1; gbase[t + 1024] = e; gcur[t + 1024] = e; }
}

// ---- partition edges into buckets: temp[pos] = (row&63)<<17 | col ----
__global__ void k_binscatter(const int* __restrict__ rows, const int* __restrict__ cols,
                             int E, int* __restrict__ gcur, uint32_t* __restrict__ temp) {
  int e = blockIdx.x * blockDim.x + threadIdx.x;
  if (e < E) {
    int r = rows[e];
    int c = cols[e];
    int b = r >> 6;
    int pos = atomicAdd(&gcur[b], 1);
    temp[pos] = ((uint32_t)(r & 63) << 17) | (uint32_t)c;
  }
}

// ---- fp32 GEMM: h[m][n] = sum_k x[m][k] W[k][n] + b[n] ----
// hu[m*64 + j] packs bf16 feats (j, j+64). block 256, tile M=64, N=128, K staged 64.
__launch_bounds__(256)
__global__ void k_gemm(const float* __restrict__ x, const float* __restrict__ W,
                       const float* __restrict__ bias, uint32_t* __restrict__ hu, int M) {
  __shared__ float xs[64][68];    // +4 pad
  __shared__ float ws[64][132];   // +4 pad
  int tid = threadIdx.x;
  int tx = tid & 31;   // covers cols {2tx, 2tx+1, 2tx+64, 2tx+65}
  int ty = tid >> 5;   // covers rows ty + 8*i
  int m0 = blockIdx.x * 64;
  float acc[8][4];
#pragma unroll
  for (int i = 0; i < 8; ++i)
#pragma unroll
    for (int j = 0; j < 4; ++j) acc[i][j] = 0.0f;

  for (int k0 = 0; k0 < 256; k0 += 64) {
#pragma unroll
    for (int l = 0; l < 4; ++l) {           // x tile: 64x64 floats
      int li = l * 256 + tid;
      int r = li >> 4;
      int c = (li & 15) << 2;
      float4 v = make_float4(0.f, 0.f, 0.f, 0.f);
      int gm = m0 + r;
      if (gm < M) v = *(const float4*)&x[(size_t)gm * 256 + k0 + c];
      *(float4*)&xs[r][c] = v;
    }
#pragma unroll
    for (int l = 0; l < 8; ++l) {           // W tile: 64x128 floats
      int li = l * 256 + tid;
      int r = li >> 5;
      int c = (li & 31) << 2;
      *(float4*)&ws[r][c] = *(const float4*)&W[(size_t)(k0 + r) * 128 + c];
    }
    __syncthreads();
#pragma unroll 8
    for (int kk = 0; kk < 64; ++kk) {
      float a[8], w[4];
#pragma unroll
      for (int i = 0; i < 8; ++i) a[i] = xs[ty + 8 * i][kk];
      w[0] = ws[kk][2 * tx];
      w[1] = ws[kk][2 * tx + 1];
      w[2] = ws[kk][2 * tx + 64];
      w[3] = ws[kk][2 * tx + 65];
#pragma unroll
      for (int i = 0; i < 8; ++i) {
        acc[i][0] = fmaf(a[i], w[0], acc[i][0]);
        acc[i][1] = fmaf(a[i], w[1], acc[i][1]);
        acc[i][2] = fmaf(a[i], w[2], acc[i][2]);
        acc[i][3] = fmaf(a[i], w[3], acc[i][3]);
      }
    }
    __syncthreads();
  }
  float b0 = bias[2 * tx], b1 = bias[2 * tx + 1];
  float b2 = bias[2 * tx + 64], b3 = bias[2 * tx + 65];
#pragma unroll
  for (int i = 0; i < 8; ++i) {
    int m = m0 + ty + 8 * i;
    if (m < M) {
      uint2 o;
      o.x = pack_bf16(acc[i][0] + b0, acc[i][2] + b2);  // feats (2tx, 2tx+64)
      o.y = pack_bf16(acc[i][1] + b1, acc[i][3] + b3);  // feats (2tx+1, 2tx+65)
      *(uint2*)&hu[(size_t)m * 64 + 2 * tx] = o;
    }
  }
}

// ---- per-bucket aggregation: block b owns rows [64b, 64b+64), LDS fp32 acc ----
__launch_bounds__(256)
__global__ void k_bucket_agg(const uint32_t* __restrict__ hu, const float* __restrict__ dis,
                             const int* __restrict__ gbase, const int* __restrict__ bcnt,
                             const uint32_t* __restrict__ temp, float* __restrict__ out,
                             int N) {
  __shared__ float acc[64 * 128];  // 32 KB
  int b = blockIdx.x;
  int tid = threadIdx.x;
  float4 z = make_float4(0.f, 0.f, 0.f, 0.f);
  for (int i = tid; i < 2048; i += 256) *(float4*)&acc[i * 4] = z;
  __syncthreads();

  int start = gbase[b];
  int cnt = bcnt[b];
  int wv = tid >> 6;
  int lane = tid & 63;

  for (int i0 = wv * 64; i0 < cnt; i0 += 256) {
    uint32_t my = (i0 + lane < cnt) ? temp[start + i0 + lane] : 0u;
    int kmax = min(64, cnt - i0);
#pragma unroll 4
    for (int k = 0; k < kmax; ++k) {
      uint32_t pk = __shfl((int)my, k);
      int lrow = pk >> 17;
      int c = pk & 0x1FFFF;
      float w = dis[c];
      uint32_t p = hu[(size_t)c * 64 + lane];
      atomicAdd(&acc[lrow * 128 + lane], w * bf_lo(p));
      atomicAdd(&acc[lrow * 128 + 64 + lane], w * bf_hi(p));
    }
  }
  __syncthreads();

  // epilogue: self loop + final D^-1/2 scale, coalesced out write
  for (int j = wv; j < 64; j += 4) {
    int gr = b * 64 + j;
    if (gr >= N) continue;
    float di = dis[gr];
    uint32_t p = hu[(size_t)gr * 64 + lane];
    float lo = di * (acc[j * 128 + lane] + di * bf_lo(p));
    float hi = di * (acc[j * 128 + 64 + lane] + di * bf_hi(p));
    out[(size_t)gr * 128 + lane] = lo;
    out[(size_t)gr * 128 + 64 + lane] = hi;
  }
}

// ---- fallback (small workspace): per-edge atomics ----
__launch_bounds__(256)
__global__ void k_selfinit(const uint32_t* __restrict__ hu, const float* __restrict__ dis,
                           float* __restrict__ out, int N) {
  int wid = blockIdx.x * 4 + (threadIdx.x >> 6);
  int lane = threadIdx.x & 63;
  if (wid >= N) return;
  float d2 = dis[wid] * dis[wid];
  uint32_t p = hu[(size_t)wid * 64 + lane];
  out[(size_t)wid * 128 + lane] = d2 * bf_lo(p);
  out[(size_t)wid * 128 + 64 + lane] = d2 * bf_hi(p);
}

__launch_bounds__(256)
__global__ void k_edge_atomic(const int* __restrict__ rows, const int* __restrict__ cols, int E,
                              const uint32_t* __restrict__ hu, const float* __restrict__ dis,
                              float* __restrict__ out) {
  int wid = blockIdx.x * 4 + (threadIdx.x >> 6);
  int lane = threadIdx.x & 63;
  if (wid >= E) return;
  int r = rows[wid], c = cols[wid];
  float w = dis[r] * dis[c];
  uint32_t p = hu[(size_t)c * 64 + lane];
  atomicAdd(&out[(size_t)r * 128 + lane], w * bf_lo(p));
  atomicAdd(&out[(size_t)r * 128 + 64 + lane], w * bf_hi(p));
}

extern "C" void kernel_launch(void* const* d_in, const int* in_sizes, int n_in,
                              void* d_out, int out_size, void* d_ws, size_t ws_size,
                              hipStream_t stream) {
  const float* x    = (const float*)d_in[0];
  const int*   ei   = (const int*)d_in[1];
  const float* W    = (const float*)d_in[2];
  const float* bias = (const float*)d_in[3];
  float* out = (float*)d_out;

  const int N = in_sizes[0] / 256;   // 100000
  const int E = in_sizes[1] / 2;     // 3200000
  const int NB = (N + 63) / 64;      // 1563 buckets of 64 rows
  const int* rows = ei;
  const int* cols = ei + E;

  // workspace layout (256B aligned slices)
  size_t off = 0;
  auto alloc = [&](size_t bytes) -> void* {
    void* p = (char*)d_ws + off;
    off += (bytes + 255) & ~(size_t)255;
    return p;
  };
  uint32_t* hu    = (uint32_t*)alloc((size_t)N * 64 * 4);  // bf16-packed h
  float*    dis   = (float*)alloc((size_t)N * 4);
  int*      deg   = (int*)alloc((size_t)N * 4);
  int*      bcnt  = (int*)alloc((size_t)NB * 4);
  int*      gbase = (int*)alloc((size_t)NB * 4);
  int*      gcur  = (int*)alloc((size_t)NB * 4);
  size_t small_end = off;
  uint32_t* temp  = (uint32_t*)alloc((size_t)E * 4);
  bool full = (off <= ws_size);
  bool atomic_ok = (small_end <= ws_size);

  hipMemsetAsync(deg, 0, (size_t)N * 4, stream);
  k_count<<<(E + 255) / 256, 256, 0, stream>>>(rows, E, deg);
  k_dis<<<(N + 255) / 256, 256, 0, stream>>>(deg, dis, N);
  k_gemm<<<(N + 63) / 64, 256, 0, stream>>>(x, W, bias, hu, N);

  if (full) {
    k_bucketcnt<<<(NB + 3) / 4, 256, 0, stream>>>(deg, N, NB, bcnt);
    k_scanb<<<1, 1024, 0, stream>>>(bcnt, NB, gbase, gcur);
    k_binscatter<<<(E + 255) / 256, 256, 0, stream>>>(rows, cols, E, gcur, temp);
    k_bucket_agg<<<NB, 256, 0, stream>>>(hu, dis, gbase, bcnt, temp, out, N);
  } else if (atomic_ok) {
    k_selfinit<<<(N + 3) / 4, 256, 0, stream>>>(hu, dis, out, N);
    k_edge_atomic<<<(E + 3) / 4, 256, 0, stream>>>(rows, cols, E, hu, dis, out);
  }
}

// Round 3
// 862.430 us; speedup vs baseline: 3.6148x; 3.6148x over previous
//
#include <hip/hip_runtime.h>
#include <hip/hip_bf16.h>
#include <stdint.h>

// GCN layer: out = D^-1/2 (A+I) D^-1/2 (x W + b)
// N=100000 nodes, E=3.2M edges, 256 -> 128 features.
// Pipeline: degree count -> rsqrt -> fp32 GEMM (stores hu' = bf16(dis*h),
// lane j packs feats (j, j+64)) -> bucket partition (64 rows/bucket, L2-resident
// cursors) -> per-bucket CSR build (contiguous 8KB windows, no write amp) ->
// wave-per-node register-accumulating gather aggregation.

__device__ __forceinline__ float bf_lo(uint32_t p) { return __uint_as_float(p << 16); }
__device__ __forceinline__ float bf_hi(uint32_t p) { return __uint_as_float(p & 0xffff0000u); }

__device__ __forceinline__ uint32_t f2bf(float f) {
  uint32_t u = __float_as_uint(f);
  return (u + 0x7fffu + ((u >> 16) & 1u)) >> 16;  // RNE
}
__device__ __forceinline__ uint32_t pack_bf16(float lo, float hi) {
  return (f2bf(hi) << 16) | f2bf(lo);
}

// ---- degree count ----
__global__ void k_count(const int* __restrict__ rows, int E, int* __restrict__ deg) {
  int e = blockIdx.x * blockDim.x + threadIdx.x;
  if (e < E) atomicAdd(&deg[rows[e]], 1);
}

// ---- d^-1/2 (deg includes +1 self loop) ----
__global__ void k_dis(const int* __restrict__ deg, float* __restrict__ dis, int N) {
  int i = blockIdx.x * blockDim.x + threadIdx.x;
  if (i < N) dis[i] = rsqrtf((float)(deg[i] + 1));
}

// ---- per-bucket edge counts: bcnt[b] = sum deg[64b .. 64b+63] ----
__global__ void k_bucketcnt(const int* __restrict__ deg, int N, int NB,
                            int* __restrict__ bcnt) {
  int b = blockIdx.x * 4 + (threadIdx.x >> 6);
  int lane = threadIdx.x & 63;
  if (b >= NB) return;
  int r = b * 64 + lane;
  int v = (r < N) ? deg[r] : 0;
  for (int d = 32; d; d >>= 1) v += __shfl_down(v, d);
  if (lane == 0) bcnt[b] = v;
}

// ---- exclusive scan of bucket counts (single block, n <= 2048) ----
__global__ void k_scanb(const int* __restrict__ bcnt, int n,
                        int* __restrict__ gbase, int* __restrict__ gcur) {
  __shared__ int s[2048];
  int t = threadIdx.x;  // 1024 threads
  int v0 = (t < n) ? bcnt[t] : 0;
  int v1 = (t + 1024 < n) ? bcnt[t + 1024] : 0;
  s[t] = v0; s[t + 1024] = v1;
  __syncthreads();
  for (int d = 1; d < 2048; d <<= 1) {
    int a0 = (t >= d) ? s[t - d] : 0;
    int a1 = s[t + 1024 - d];  // t+1024 >= d always (d <= 1024)
    __syncthreads();
    s[t] += a0; s[t + 1024] += a1;
    __syncthreads();
  }
  if (t < n)        { int e = s[t] - v0;        gbase[t] = e;        gcur[t] = e; }
  if (t + 1024 < n) { int e = s[t + 1024] - v1; gbase[t + 1024] = e; gcur[t + 1024] = e; }
}

// ---- partition edges into buckets: temp[pos] = (row&63)<<17 | col ----
// 1563 cursors -> ~100KB of active write lines, L2-resident, no write amp.
__global__ void k_binscatter(const int* __restrict__ rows, const int* __restrict__ cols,
                             int E, int* __restrict__ gcur, uint32_t* __restrict__ temp) {
  int e = blockIdx.x * blockDim.x + threadIdx.x;
  if (e < E) {
    int r = rows[e];
    int c = cols[e];
    int b = r >> 6;
    int pos = atomicAdd(&gcur[b], 1);
    temp[pos] = ((uint32_t)(r & 63) << 17) | (uint32_t)c;
  }
}

// ---- per-bucket CSR build: block b sorts its bucket into csr + writes offs ----
// Destination window = bucket's contiguous CSR range (~8KB) -> stays in L2.
__launch_bounds__(256)
__global__ void k_csr_build(const int* __restrict__ deg, const int* __restrict__ gbase,
                            const int* __restrict__ bcnt, const uint32_t* __restrict__ temp,
                            int N, int NB, int* __restrict__ offs, int* __restrict__ csr) {
  __shared__ int lcur[64];
  int b = blockIdx.x;
  int tid = threadIdx.x;
  int base = gbase[b];
  int cnt = bcnt[b];

  if (tid < 64) {
    int r = b * 64 + tid;
    int d = (r < N) ? deg[r] : 0;
    // wave-wide inclusive scan over 64 lanes
    int inc = d;
    for (int o = 1; o < 64; o <<= 1) {
      int t = __shfl_up(inc, o);
      if (tid >= o) inc += t;
    }
    int ex = inc - d;
    if (r < N) offs[r] = base + ex;
    lcur[tid] = ex;  // intra-bucket cursor start
  }
  __syncthreads();

  for (int i = tid; i < cnt; i += 256) {
    uint32_t pk = temp[base + i];
    int lrow = pk >> 17;
    int c = (int)(pk & 0x1FFFF);
    int p = atomicAdd(&lcur[lrow], 1);
    csr[base + p] = c;
  }
}

// ---- fp32 GEMM: h[m][n] = sum_k x[m][k] W[k][n] + b[n]; store bf16(dis[m]*h) ----
// hu[m*64 + j] packs bf16 feats (j, j+64). block 256, tile M=64, N=128, K staged 64.
__launch_bounds__(256)
__global__ void k_gemm(const float* __restrict__ x, const float* __restrict__ W,
                       const float* __restrict__ bias, const float* __restrict__ dis,
                       uint32_t* __restrict__ hu, int M) {
  __shared__ float xs[64][68];    // +4 pad
  __shared__ float ws[64][132];   // +4 pad
  int tid = threadIdx.x;
  int tx = tid & 31;   // covers cols {2tx, 2tx+1, 2tx+64, 2tx+65}
  int ty = tid >> 5;   // covers rows ty + 8*i
  int m0 = blockIdx.x * 64;
  float acc[8][4];
#pragma unroll
  for (int i = 0; i < 8; ++i)
#pragma unroll
    for (int j = 0; j < 4; ++j) acc[i][j] = 0.0f;

  for (int k0 = 0; k0 < 256; k0 += 64) {
#pragma unroll
    for (int l = 0; l < 4; ++l) {           // x tile: 64x64 floats
      int li = l * 256 + tid;
      int r = li >> 4;
      int c = (li & 15) << 2;
      float4 v = make_float4(0.f, 0.f, 0.f, 0.f);
      int gm = m0 + r;
      if (gm < M) v = *(const float4*)&x[(size_t)gm * 256 + k0 + c];
      *(float4*)&xs[r][c] = v;
    }
#pragma unroll
    for (int l = 0; l < 8; ++l) {           // W tile: 64x128 floats
      int li = l * 256 + tid;
      int r = li >> 5;
      int c = (li & 31) << 2;
      *(float4*)&ws[r][c] = *(const float4*)&W[(size_t)(k0 + r) * 128 + c];
    }
    __syncthreads();
#pragma unroll 8
    for (int kk = 0; kk < 64; ++kk) {
      float a[8], w[4];
#pragma unroll
      for (int i = 0; i < 8; ++i) a[i] = xs[ty + 8 * i][kk];
      w[0] = ws[kk][2 * tx];
      w[1] = ws[kk][2 * tx + 1];
      w[2] = ws[kk][2 * tx + 64];
      w[3] = ws[kk][2 * tx + 65];
#pragma unroll
      for (int i = 0; i < 8; ++i) {
        acc[i][0] = fmaf(a[i], w[0], acc[i][0]);
        acc[i][1] = fmaf(a[i], w[1], acc[i][1]);
        acc[i][2] = fmaf(a[i], w[2], acc[i][2]);
        acc[i][3] = fmaf(a[i], w[3], acc[i][3]);
      }
    }
    __syncthreads();
  }
  float b0 = bias[2 * tx], b1 = bias[2 * tx + 1];
  float b2 = bias[2 * tx + 64], b3 = bias[2 * tx + 65];
#pragma unroll
  for (int i = 0; i < 8; ++i) {
    int m = m0 + ty + 8 * i;
    if (m < M) {
      float di = dis[m];
      uint2 o;
      o.x = pack_bf16(di * (acc[i][0] + b0), di * (acc[i][2] + b2));  // (2tx, 2tx+64)
      o.y = pack_bf16(di * (acc[i][1] + b1), di * (acc[i][3] + b3));  // (2tx+1, 2tx+65)
      *(uint2*)&hu[(size_t)m * 64 + 2 * tx] = o;
    }
  }
}

// ---- aggregation: wave per node, register accumulate; out[i] = dis[i]*(sum+self) ----
__launch_bounds__(256)
__global__ void k_aggregate(const uint32_t* __restrict__ hu, const float* __restrict__ dis,
                            const int* __restrict__ offs, const int* __restrict__ csr,
                            float* __restrict__ out, int N, int E) {
  int wid = blockIdx.x * 4 + (threadIdx.x >> 6);
  int lane = threadIdx.x & 63;
  if (wid >= N) return;
  uint32_t ps = hu[(size_t)wid * 64 + lane];
  float ax = bf_lo(ps);   // self loop: hu' already has dis folded in
  float ay = bf_hi(ps);
  int e = offs[wid];
  int end = (wid + 1 < N) ? offs[wid + 1] : E;
  for (; e + 3 < end; e += 4) {
    int c0 = csr[e], c1 = csr[e + 1], c2 = csr[e + 2], c3 = csr[e + 3];
    uint32_t p0 = hu[(size_t)c0 * 64 + lane];
    uint32_t p1 = hu[(size_t)c1 * 64 + lane];
    uint32_t p2 = hu[(size_t)c2 * 64 + lane];
    uint32_t p3 = hu[(size_t)c3 * 64 + lane];
    ax += bf_lo(p0) + bf_lo(p1) + bf_lo(p2) + bf_lo(p3);
    ay += bf_hi(p0) + bf_hi(p1) + bf_hi(p2) + bf_hi(p3);
  }
  for (; e < end; ++e) {
    int c = csr[e];
    uint32_t p = hu[(size_t)c * 64 + lane];
    ax += bf_lo(p);
    ay += bf_hi(p);
  }
  float di = dis[wid];
  out[(size_t)wid * 128 + lane] = di * ax;
  out[(size_t)wid * 128 + 64 + lane] = di * ay;
}

// ---- fallback (small workspace): per-edge atomics on fp32 out ----
__launch_bounds__(256)
__global__ void k_selfinit(const uint32_t* __restrict__ hu, const float* __restrict__ dis,
                           float* __restrict__ out, int N) {
  int wid = blockIdx.x * 4 + (threadIdx.x >> 6);
  int lane = threadIdx.x & 63;
  if (wid >= N) return;
  float di = dis[wid];
  uint32_t p = hu[(size_t)wid * 64 + lane];
  out[(size_t)wid * 128 + lane] = di * bf_lo(p);
  out[(size_t)wid * 128 + 64 + lane] = di * bf_hi(p);
}

__launch_bounds__(256)
__global__ void k_edge_atomic(const int* __restrict__ rows, const int* __restrict__ cols, int E,
                              const uint32_t* __restrict__ hu, const float* __restrict__ dis,
                              float* __restrict__ out) {
  int wid = blockIdx.x * 4 + (threadIdx.x >> 6);
  int lane = threadIdx.x & 63;
  if (wid >= E) return;
  int r = rows[wid], c = cols[wid];
  float w = dis[r];  // hu'[c] already carries dis[c]
  uint32_t p = hu[(size_t)c * 64 + lane];
  atomicAdd(&out[(size_t)r * 128 + lane], w * bf_lo(p));
  atomicAdd(&out[(size_t)r * 128 + 64 + lane], w * bf_hi(p));
}

extern "C" void kernel_launch(void* const* d_in, const int* in_sizes, int n_in,
                              void* d_out, int out_size, void* d_ws, size_t ws_size,
                              hipStream_t stream) {
  const float* x    = (const float*)d_in[0];
  const int*   ei   = (const int*)d_in[1];
  const float* W    = (const float*)d_in[2];
  const float* bias = (const float*)d_in[3];
  float* out = (float*)d_out;

  const int N = in_sizes[0] / 256;   // 100000
  const int E = in_sizes[1] / 2;     // 3200000
  const int NB = (N + 63) / 64;      // 1563 buckets of 64 rows
  const int* rows = ei;
  const int* cols = ei + E;

  // workspace layout (256B aligned slices)
  size_t off = 0;
  auto alloc = [&](size_t bytes) -> void* {
    void* p = (char*)d_ws + off;
    off += (bytes + 255) & ~(size_t)255;
    return p;
  };
  uint32_t* hu    = (uint32_t*)alloc((size_t)N * 64 * 4);  // bf16-packed dis*h
  float*    dis   = (float*)alloc((size_t)N * 4);
  int*      deg   = (int*)alloc((size_t)N * 4);
  int*      bcnt  = (int*)alloc((size_t)NB * 4);
  int*      gbase = (int*)alloc((size_t)NB * 4);
  int*      gcur  = (int*)alloc((size_t)NB * 4);
  int*      offs  = (int*)alloc((size_t)N * 4);
  size_t small_end = off;
  uint32_t* temp  = (uint32_t*)alloc((size_t)E * 4);
  int*      csr   = (int*)alloc((size_t)E * 4);
  bool full = (off <= ws_size);
  bool atomic_ok = (small_end <= ws_size);

  hipMemsetAsync(deg, 0, (size_t)N * 4, stream);
  k_count<<<(E + 255) / 256, 256, 0, stream>>>(rows, E, deg);
  k_dis<<<(N + 255) / 256, 256, 0, stream>>>(deg, dis, N);
  k_gemm<<<(N + 63) / 64, 256, 0, stream>>>(x, W, bias, dis, hu, N);

  if (full) {
    k_bucketcnt<<<(NB + 3) / 4, 256, 0, stream>>>(deg, N, NB, bcnt);
    k_scanb<<<1, 1024, 0, stream>>>(bcnt, NB, gbase, gcur);
    k_binscatter<<<(E + 255) / 256, 256, 0, stream>>>(rows, cols, E, gcur, temp);
    k_csr_build<<<NB, 256, 0, stream>>>(deg, gbase, bcnt, temp, N, NB, offs, csr);
    k_aggregate<<<(N + 3) / 4, 256, 0, stream>>>(hu, dis, offs, csr, out, N, E);
  } else if (atomic_ok) {
    k_selfinit<<<(N + 3) / 4, 256, 0, stream>>>(hu, dis, out, N);
    k_edge_atomic<<<(E + 3) / 4, 256, 0, stream>>>(rows, cols, E, hu, dis, out);
  }
}

// Round 4
// 449.275 us; speedup vs baseline: 6.9390x; 1.9196x over previous
//
#include <hip/hip_runtime.h>
#include <hip/hip_bf16.h>
#include <stdint.h>

// GCN layer: out = D^-1/2 (A+I) D^-1/2 (x W + b)
// N=100000 nodes, E=3.2M edges, 256 -> 128 features.
// Pipeline: degree count -> rsqrt -> fp32 GEMM (stores hu' = bf16(dis*h),
// lane j packs feats (j, j+64)) -> LDS-staged bucket partition (512 rows/bucket,
// burst writes, one reservation atomic per block x bucket) -> per-bucket CSR
// build (L2-resident windows) -> wave-per-node register-accumulating gather.

#define RB    512      // rows per bucket
#define RBSH  9
#define NBMAX 256      // >= NB = ceil(100000/512) = 196
#define CHUNK 12288    // edges per partition block (LDS sorted array = 48 KB)

__device__ __forceinline__ float bf_lo(uint32_t p) { return __uint_as_float(p << 16); }
__device__ __forceinline__ float bf_hi(uint32_t p) { return __uint_as_float(p & 0xffff0000u); }

__device__ __forceinline__ uint32_t f2bf(float f) {
  uint32_t u = __float_as_uint(f);
  return (u + 0x7fffu + ((u >> 16) & 1u)) >> 16;  // RNE
}
__device__ __forceinline__ uint32_t pack_bf16(float lo, float hi) {
  return (f2bf(hi) << 16) | f2bf(lo);
}

// ---- degree count ----
__global__ void k_count(const int* __restrict__ rows, int E, int* __restrict__ deg) {
  int e = blockIdx.x * blockDim.x + threadIdx.x;
  if (e < E) atomicAdd(&deg[rows[e]], 1);
}

// ---- d^-1/2 (deg includes +1 self loop) ----
__global__ void k_dis(const int* __restrict__ deg, float* __restrict__ dis, int N) {
  int i = blockIdx.x * blockDim.x + threadIdx.x;
  if (i < N) dis[i] = rsqrtf((float)(deg[i] + 1));
}

// ---- bucket histogram (LDS-staged, few global atomics) ----
__launch_bounds__(256)
__global__ void k_bhist(const int* __restrict__ rows, int E, int NB,
                        int* __restrict__ bcnt) {
  __shared__ int h[NBMAX];
  int tid = threadIdx.x;
  for (int i = tid; i < NBMAX; i += 256) h[i] = 0;
  __syncthreads();
  int stride = gridDim.x * 256;
  for (int e = blockIdx.x * 256 + tid; e < E; e += stride)
    atomicAdd(&h[rows[e] >> RBSH], 1);
  __syncthreads();
  for (int b = tid; b < NB; b += 256)
    if (h[b]) atomicAdd(&bcnt[b], h[b]);
}

// ---- exclusive scan of bucket counts (single block, n <= 2048) ----
__global__ void k_scanb(const int* __restrict__ bcnt, int n,
                        int* __restrict__ gbase, int* __restrict__ gcur) {
  __shared__ int s[2048];
  int t = threadIdx.x;  // 1024 threads
  int v0 = (t < n) ? bcnt[t] : 0;
  int v1 = (t + 1024 < n) ? bcnt[t + 1024] : 0;
  s[t] = v0; s[t + 1024] = v1;
  __syncthreads();
  for (int d = 1; d < 2048; d <<= 1) {
    int a0 = (t >= d) ? s[t - d] : 0;
    int a1 = s[t + 1024 - d];
    __syncthreads();
    s[t] += a0; s[t + 1024] += a1;
    __syncthreads();
  }
  if (t < n)        { int e = s[t] - v0;        gbase[t] = e;        gcur[t] = e; }
  if (t + 1024 < n) { int e = s[t + 1024] - v1; gbase[t + 1024] = e; gcur[t + 1024] = e; }
}

// ---- LDS-staged partition: chunk -> bucket-sorted runs -> burst copy-out ----
__launch_bounds__(1024)
__global__ void k_part(const int* __restrict__ rows, const int* __restrict__ cols,
                       int E, int NB, int* __restrict__ gcur,
                       uint32_t* __restrict__ temp) {
  __shared__ uint32_t sorted[CHUNK];  // 48 KB
  __shared__ int hist[NBMAX];         // histogram, then intra-chunk cursor
  __shared__ int scanv[NBMAX];        // inclusive scan (run boundaries)
  __shared__ int res[NBMAX];          // global reservation base per bucket
  int tid = threadIdx.x;
  int base = blockIdx.x * CHUNK;
  int cnt = min(CHUNK, E - base);

  for (int i = tid; i < NBMAX; i += 1024) hist[i] = 0;
  __syncthreads();
  for (int i = tid; i < cnt; i += 1024)
    atomicAdd(&hist[rows[base + i] >> RBSH], 1);
  __syncthreads();
  if (tid < NBMAX) scanv[tid] = hist[tid];
  __syncthreads();
  for (int d = 1; d < NBMAX; d <<= 1) {
    int v = 0;
    if (tid < NBMAX && tid >= d) v = scanv[tid - d];
    __syncthreads();
    if (tid < NBMAX) scanv[tid] += v;
    __syncthreads();
  }
  if (tid < NB) {
    int c = hist[tid];
    res[tid] = c ? atomicAdd(&gcur[tid], c) : 0;  // one reservation per bucket
    hist[tid] = scanv[tid] - c;                   // lbase -> cursor
  }
  __syncthreads();
  for (int i = tid; i < cnt; i += 1024) {
    int r = rows[base + i];
    int c = cols[base + i];
    int b = r >> RBSH;
    int p = atomicAdd(&hist[b], 1);
    sorted[p] = ((uint32_t)(r & (RB - 1)) << 17) | (uint32_t)c;
  }
  __syncthreads();
  int wv = tid >> 6, lane = tid & 63;
  for (int b = wv; b < NB; b += 16) {   // wave-cooperative contiguous run copy
    int st = b ? scanv[b - 1] : 0;
    int en = scanv[b];
    int gb = res[b];
    for (int j = st + lane; j < en; j += 64)
      temp[gb + (j - st)] = sorted[j];
  }
}

// ---- per-bucket CSR build: block b sorts its 512-row window into csr ----
__launch_bounds__(256)
__global__ void k_csr_build(const int* __restrict__ gbase, const int* __restrict__ bcnt,
                            const uint32_t* __restrict__ temp, int N,
                            int* __restrict__ offs, int* __restrict__ csr) {
  __shared__ int cnt[RB];   // per-node count -> exclusive base -> cursor
  __shared__ int S[256];
  int b = blockIdx.x;
  int tid = threadIdx.x;
  int base = gbase[b];
  int cb = bcnt[b];

  cnt[tid] = 0; cnt[tid + 256] = 0;
  __syncthreads();
  for (int i = tid; i < cb; i += 256)
    atomicAdd(&cnt[temp[base + i] >> 17], 1);
  __syncthreads();
  int a0 = cnt[2 * tid], a1 = cnt[2 * tid + 1];
  S[tid] = a0 + a1;
  __syncthreads();
  for (int d = 1; d < 256; d <<= 1) {
    int v = (tid >= d) ? S[tid - d] : 0;
    __syncthreads();
    S[tid] += v;
    __syncthreads();
  }
  int ex0 = S[tid] - (a0 + a1);
  int r0 = b * RB + 2 * tid;
  if (r0 < N)     offs[r0]     = base + ex0;
  if (r0 + 1 < N) offs[r0 + 1] = base + ex0 + a0;
  cnt[2 * tid]     = ex0;       // cursor start
  cnt[2 * tid + 1] = ex0 + a0;
  __syncthreads();
  for (int i = tid; i < cb; i += 256) {
    uint32_t pk = temp[base + i];
    int lrow = pk >> 17;
    int c = (int)(pk & 0x1FFFF);
    int p = atomicAdd(&cnt[lrow], 1);
    csr[base + p] = c;
  }
}

// ---- fp32 GEMM: h[m][n] = sum_k x[m][k] W[k][n] + b[n]; store bf16(dis[m]*h) ----
// hu[m*64 + j] packs bf16 feats (j, j+64). block 256, tile M=64, N=128, K staged 64.
__launch_bounds__(256)
__global__ void k_gemm(const float* __restrict__ x, const float* __restrict__ W,
                       const float* __restrict__ bias, const float* __restrict__ dis,
                       uint32_t* __restrict__ hu, int M) {
  __shared__ float xs[64][68];    // +4 pad
  __shared__ float ws[64][132];   // +4 pad
  int tid = threadIdx.x;
  int tx = tid & 31;
  int ty = tid >> 5;
  int m0 = blockIdx.x * 64;
  float acc[8][4];
#pragma unroll
  for (int i = 0; i < 8; ++i)
#pragma unroll
    for (int j = 0; j < 4; ++j) acc[i][j] = 0.0f;

  for (int k0 = 0; k0 < 256; k0 += 64) {
#pragma unroll
    for (int l = 0; l < 4; ++l) {
      int li = l * 256 + tid;
      int r = li >> 4;
      int c = (li & 15) << 2;
      float4 v = make_float4(0.f, 0.f, 0.f, 0.f);
      int gm = m0 + r;
      if (gm < M) v = *(const float4*)&x[(size_t)gm * 256 + k0 + c];
      *(float4*)&xs[r][c] = v;
    }
#pragma unroll
    for (int l = 0; l < 8; ++l) {
      int li = l * 256 + tid;
      int r = li >> 5;
      int c = (li & 31) << 2;
      *(float4*)&ws[r][c] = *(const float4*)&W[(size_t)(k0 + r) * 128 + c];
    }
    __syncthreads();
#pragma unroll 8
    for (int kk = 0; kk < 64; ++kk) {
      float a[8], w[4];
#pragma unroll
      for (int i = 0; i < 8; ++i) a[i] = xs[ty + 8 * i][kk];
      w[0] = ws[kk][2 * tx];
      w[1] = ws[kk][2 * tx + 1];
      w[2] = ws[kk][2 * tx + 64];
      w[3] = ws[kk][2 * tx + 65];
#pragma unroll
      for (int i = 0; i < 8; ++i) {
        acc[i][0] = fmaf(a[i], w[0], acc[i][0]);
        acc[i][1] = fmaf(a[i], w[1], acc[i][1]);
        acc[i][2] = fmaf(a[i], w[2], acc[i][2]);
        acc[i][3] = fmaf(a[i], w[3], acc[i][3]);
      }
    }
    __syncthreads();
  }
  float b0 = bias[2 * tx], b1 = bias[2 * tx + 1];
  float b2 = bias[2 * tx + 64], b3 = bias[2 * tx + 65];
#pragma unroll
  for (int i = 0; i < 8; ++i) {
    int m = m0 + ty + 8 * i;
    if (m < M) {
      float di = dis[m];
      uint2 o;
      o.x = pack_bf16(di * (acc[i][0] + b0), di * (acc[i][2] + b2));
      o.y = pack_bf16(di * (acc[i][1] + b1), di * (acc[i][3] + b3));
      *(uint2*)&hu[(size_t)m * 64 + 2 * tx] = o;
    }
  }
}

// ---- aggregation: wave per node, register accumulate; out[i] = dis[i]*(sum+self) ----
__launch_bounds__(256)
__global__ void k_aggregate(const uint32_t* __restrict__ hu, const float* __restrict__ dis,
                            const int* __restrict__ offs, const int* __restrict__ csr,
                            float* __restrict__ out, int N, int E) {
  int wid = blockIdx.x * 4 + (threadIdx.x >> 6);
  int lane = threadIdx.x & 63;
  if (wid >= N) return;
  uint32_t ps = hu[(size_t)wid * 64 + lane];
  float ax = bf_lo(ps);   // self loop: hu' already has dis folded in
  float ay = bf_hi(ps);
  int e = offs[wid];
  int end = (wid + 1 < N) ? offs[wid + 1] : E;
  for (; e + 3 < end; e += 4) {
    int c0 = csr[e], c1 = csr[e + 1], c2 = csr[e + 2], c3 = csr[e + 3];
    uint32_t p0 = hu[(size_t)c0 * 64 + lane];
    uint32_t p1 = hu[(size_t)c1 * 64 + lane];
    uint32_t p2 = hu[(size_t)c2 * 64 + lane];
    uint32_t p3 = hu[(size_t)c3 * 64 + lane];
    ax += bf_lo(p0) + bf_lo(p1) + bf_lo(p2) + bf_lo(p3);
    ay += bf_hi(p0) + bf_hi(p1) + bf_hi(p2) + bf_hi(p3);
  }
  for (; e < end; ++e) {
    int c = csr[e];
    uint32_t p = hu[(size_t)c * 64 + lane];
    ax += bf_lo(p);
    ay += bf_hi(p);
  }
  float di = dis[wid];
  out[(size_t)wid * 128 + lane] = di * ax;
  out[(size_t)wid * 128 + 64 + lane] = di * ay;
}

// ---- fallback (small workspace): per-edge atomics on fp32 out ----
__launch_bounds__(256)
__global__ void k_selfinit(const uint32_t* __restrict__ hu, const float* __restrict__ dis,
                           float* __restrict__ out, int N) {
  int wid = blockIdx.x * 4 + (threadIdx.x >> 6);
  int lane = threadIdx.x & 63;
  if (wid >= N) return;
  float di = dis[wid];
  uint32_t p = hu[(size_t)wid * 64 + lane];
  out[(size_t)wid * 128 + lane] = di * bf_lo(p);
  out[(size_t)wid * 128 + 64 + lane] = di * bf_hi(p);
}

__launch_bounds__(256)
__global__ void k_edge_atomic(const int* __restrict__ rows, const int* __restrict__ cols, int E,
                              const uint32_t* __restrict__ hu, const float* __restrict__ dis,
                              float* __restrict__ out) {
  int wid = blockIdx.x * 4 + (threadIdx.x >> 6);
  int lane = threadIdx.x & 63;
  if (wid >= E) return;
  int r = rows[wid], c = cols[wid];
  float w = dis[r];  // hu'[c] already carries dis[c]
  uint32_t p = hu[(size_t)c * 64 + lane];
  atomicAdd(&out[(size_t)r * 128 + lane], w * bf_lo(p));
  atomicAdd(&out[(size_t)r * 128 + 64 + lane], w * bf_hi(p));
}

extern "C" void kernel_launch(void* const* d_in, const int* in_sizes, int n_in,
                              void* d_out, int out_size, void* d_ws, size_t ws_size,
                              hipStream_t stream) {
  const float* x    = (const float*)d_in[0];
  const int*   ei   = (const int*)d_in[1];
  const float* W    = (const float*)d_in[2];
  const float* bias = (const float*)d_in[3];
  float* out = (float*)d_out;

  const int N = in_sizes[0] / 256;   // 100000
  const int E = in_sizes[1] / 2;     // 3200000
  const int NB = (N + RB - 1) / RB;  // 196 buckets of 512 rows
  const int* rows = ei;
  const int* cols = ei + E;

  // workspace layout (256B aligned slices)
  size_t off = 0;
  auto alloc = [&](size_t bytes) -> void* {
    void* p = (char*)d_ws + off;
    off += (bytes + 255) & ~(size_t)255;
    return p;
  };
  uint32_t* hu    = (uint32_t*)alloc((size_t)N * 64 * 4);  // bf16-packed dis*h
  float*    dis   = (float*)alloc((size_t)N * 4);
  int*      deg   = (int*)alloc((size_t)N * 4);
  int*      bcnt  = (int*)alloc((size_t)NBMAX * 4);
  int*      gbase = (int*)alloc((size_t)NBMAX * 4);
  int*      gcur  = (int*)alloc((size_t)NBMAX * 4);
  int*      offs  = (int*)alloc((size_t)N * 4);
  size_t small_end = off;
  uint32_t* temp  = (uint32_t*)alloc((size_t)E * 4);
  int*      csr   = (int*)alloc((size_t)E * 4);
  bool full = (off <= ws_size);
  bool atomic_ok = (small_end <= ws_size);

  hipMemsetAsync(deg, 0, (size_t)N * 4, stream);
  k_count<<<(E + 255) / 256, 256, 0, stream>>>(rows, E, deg);
  k_dis<<<(N + 255) / 256, 256, 0, stream>>>(deg, dis, N);
  k_gemm<<<(N + 63) / 64, 256, 0, stream>>>(x, W, bias, dis, hu, N);

  if (full) {
    hipMemsetAsync(bcnt, 0, (size_t)NBMAX * 4, stream);
    k_bhist<<<512, 256, 0, stream>>>(rows, E, NB, bcnt);
    k_scanb<<<1, 1024, 0, stream>>>(bcnt, NB, gbase, gcur);
    k_part<<<(E + CHUNK - 1) / CHUNK, 1024, 0, stream>>>(rows, cols, E, NB, gcur, temp);
    k_csr_build<<<NB, 256, 0, stream>>>(gbase, bcnt, temp, N, offs, csr);
    k_aggregate<<<(N + 3) / 4, 256, 0, stream>>>(hu, dis, offs, csr, out, N, E);
  } else if (atomic_ok) {
    k_selfinit<<<(N + 3) / 4, 256, 0, stream>>>(hu, dis, out, N);
    k_edge_atomic<<<(E + 3) / 4, 256, 0, stream>>>(rows, cols, E, hu, dis, out);
  }
}

// Round 5
// 264.419 us; speedup vs baseline: 11.7900x; 1.6991x over previous
//
#include <hip/hip_runtime.h>
#include <hip/hip_bf16.h>
#include <stdint.h>

// GCN layer: out = D^-1/2 (A+I) D^-1/2 (x W + b)
// N=100000 nodes, E=3.2M edges, 256 -> 128 features.
// Pipeline: W pre-cast to bf16 [col][k] -> bucket histogram/scan -> LDS-staged
// partition (512 rows/bucket, burst writes) -> per-bucket CSR build (also
// produces deg -> dis, so no k_count) -> bf16 MFMA GEMM (stores
// hu' = bf16(dis*h), lane j packs feat pair (p, p+32)) -> wave-per-node gather.

#define RB    512      // rows per bucket
#define RBSH  9
#define NBMAX 256      // >= NB = ceil(100000/512) = 196
#define CHUNK 12288    // edges per partition block (LDS sorted array = 48 KB)

typedef __attribute__((ext_vector_type(8))) short short8v;   // 8 bf16
typedef __attribute__((ext_vector_type(16))) float f32x16;

__device__ __forceinline__ float bf_lo(uint32_t p) { return __uint_as_float(p << 16); }
__device__ __forceinline__ float bf_hi(uint32_t p) { return __uint_as_float(p & 0xffff0000u); }

__device__ __forceinline__ uint32_t f2bf(float f) {
  uint32_t u = __float_as_uint(f);
  return (u + 0x7fffu + ((u >> 16) & 1u)) >> 16;  // RNE
}
__device__ __forceinline__ uint32_t pack_bf16(float lo, float hi) {
  return (f2bf(hi) << 16) | f2bf(lo);
}

// ---- W cast: wbf[col*256 + k] = bf16(W[k*128 + col]) ----
__global__ void k_wcast(const float* __restrict__ W, uint16_t* __restrict__ wbf) {
  int t = blockIdx.x * 256 + threadIdx.x;   // 32768 total
  int col = t >> 8, k = t & 255;
  wbf[t] = (uint16_t)f2bf(W[k * 128 + col]);
}

// ---- bucket histogram (LDS-staged, few global atomics) ----
__launch_bounds__(256)
__global__ void k_bhist(const int* __restrict__ rows, int E, int NB,
                        int* __restrict__ bcnt) {
  __shared__ int h[NBMAX];
  int tid = threadIdx.x;
  for (int i = tid; i < NBMAX; i += 256) h[i] = 0;
  __syncthreads();
  int stride = gridDim.x * 256;
  for (int e = blockIdx.x * 256 + tid; e < E; e += stride)
    atomicAdd(&h[rows[e] >> RBSH], 1);
  __syncthreads();
  for (int b = tid; b < NB; b += 256)
    if (h[b]) atomicAdd(&bcnt[b], h[b]);
}

// ---- exclusive scan of bucket counts (single block, n <= 2048) ----
__global__ void k_scanb(const int* __restrict__ bcnt, int n,
                        int* __restrict__ gbase, int* __restrict__ gcur) {
  __shared__ int s[2048];
  int t = threadIdx.x;  // 1024 threads
  int v0 = (t < n) ? bcnt[t] : 0;
  int v1 = (t + 1024 < n) ? bcnt[t + 1024] : 0;
  s[t] = v0; s[t + 1024] = v1;
  __syncthreads();
  for (int d = 1; d < 2048; d <<= 1) {
    int a0 = (t >= d) ? s[t - d] : 0;
    int a1 = s[t + 1024 - d];
    __syncthreads();
    s[t] += a0; s[t + 1024] += a1;
    __syncthreads();
  }
  if (t < n)        { int e = s[t] - v0;        gbase[t] = e;        gcur[t] = e; }
  if (t + 1024 < n) { int e = s[t + 1024] - v1; gbase[t + 1024] = e; gcur[t + 1024] = e; }
}

// ---- LDS-staged partition: chunk -> bucket-sorted runs -> burst copy-out ----
__launch_bounds__(1024)
__global__ void k_part(const int* __restrict__ rows, const int* __restrict__ cols,
                       int E, int NB, int* __restrict__ gcur,
                       uint32_t* __restrict__ temp) {
  __shared__ uint32_t sorted[CHUNK];  // 48 KB
  __shared__ int hist[NBMAX];
  __shared__ int scanv[NBMAX];
  __shared__ int res[NBMAX];
  int tid = threadIdx.x;
  int base = blockIdx.x * CHUNK;
  int cnt = min(CHUNK, E - base);

  for (int i = tid; i < NBMAX; i += 1024) hist[i] = 0;
  __syncthreads();
  for (int i = tid; i < cnt; i += 1024)
    atomicAdd(&hist[rows[base + i] >> RBSH], 1);
  __syncthreads();
  if (tid < NBMAX) scanv[tid] = hist[tid];
  __syncthreads();
  for (int d = 1; d < NBMAX; d <<= 1) {
    int v = 0;
    if (tid < NBMAX && tid >= d) v = scanv[tid - d];
    __syncthreads();
    if (tid < NBMAX) scanv[tid] += v;
    __syncthreads();
  }
  if (tid < NB) {
    int c = hist[tid];
    res[tid] = c ? atomicAdd(&gcur[tid], c) : 0;  // one reservation per bucket
    hist[tid] = scanv[tid] - c;                   // lbase -> cursor
  }
  __syncthreads();
  for (int i = tid; i < cnt; i += 1024) {
    int r = rows[base + i];
    int c = cols[base + i];
    int b = r >> RBSH;
    int p = atomicAdd(&hist[b], 1);
    sorted[p] = ((uint32_t)(r & (RB - 1)) << 17) | (uint32_t)c;
  }
  __syncthreads();
  int wv = tid >> 6, lane = tid & 63;
  for (int b = wv; b < NB; b += 16) {   // wave-cooperative contiguous run copy
    int st = b ? scanv[b - 1] : 0;
    int en = scanv[b];
    int gb = res[b];
    for (int j = st + lane; j < en; j += 64)
      temp[gb + (j - st)] = sorted[j];
  }
}

// ---- per-bucket CSR build; also emits deg -> dis (no separate count pass) ----
__launch_bounds__(256)
__global__ void k_csr_build(const int* __restrict__ gbase, const int* __restrict__ bcnt,
                            const uint32_t* __restrict__ temp, int N,
                            int* __restrict__ offs, float* __restrict__ dis,
                            int* __restrict__ csr) {
  __shared__ int cnt[RB];   // per-node count -> exclusive base -> cursor
  __shared__ int S[256];
  int b = blockIdx.x;
  int tid = threadIdx.x;
  int base = gbase[b];
  int cb = bcnt[b];

  cnt[tid] = 0; cnt[tid + 256] = 0;
  __syncthreads();
  for (int i = tid; i < cb; i += 256)
    atomicAdd(&cnt[temp[base + i] >> 17], 1);
  __syncthreads();
  int a0 = cnt[2 * tid], a1 = cnt[2 * tid + 1];
  int r0 = b * RB + 2 * tid;
  if (r0 < N)     dis[r0]     = rsqrtf((float)(a0 + 1));  // deg + self loop
  if (r0 + 1 < N) dis[r0 + 1] = rsqrtf((float)(a1 + 1));
  S[tid] = a0 + a1;
  __syncthreads();
  for (int d = 1; d < 256; d <<= 1) {
    int v = (tid >= d) ? S[tid - d] : 0;
    __syncthreads();
    S[tid] += v;
    __syncthreads();
  }
  int ex0 = S[tid] - (a0 + a1);
  if (r0 < N)     offs[r0]     = base + ex0;
  if (r0 + 1 < N) offs[r0 + 1] = base + ex0 + a0;
  cnt[2 * tid]     = ex0;
  cnt[2 * tid + 1] = ex0 + a0;
  __syncthreads();
  for (int i = tid; i < cb; i += 256) {
    uint32_t pk = temp[base + i];
    int lrow = pk >> 17;
    int c = (int)(pk & 0x1FFFF);
    int p = atomicAdd(&cnt[lrow], 1);
    csr[base + p] = c;
  }
}

// ---- bf16 MFMA GEMM: h = x W + b; store hu[m*64+j] = bf16(dis[m]*h) pair ----
// Block: 256 thr = 4 waves, M-tile 64, all 128 cols. Wave w: rows
// [32(w&1),+32), cols [64(w>>1),+64) as two 32x32 tiles. A-frags straight
// from global (x rows used once); W in LDS bf16 [col][k], 16B-slot XOR
// swizzle (slot^=col&31) => conflict-free b128 read & write.
// hu pair layout: j in [0,32) -> feats (j, j+32); j in [32,64) -> (j+32, j+64).
__launch_bounds__(256)
__global__ void k_gemm(const float* __restrict__ x, const uint16_t* __restrict__ wbf,
                       const float* __restrict__ bias, const float* __restrict__ dis,
                       uint32_t* __restrict__ hu, int M) {
  __shared__ uint16_t wlds[32768];  // 64 KB -> 2 blocks/CU
  int tid = threadIdx.x;
  {
    const uint4* src = (const uint4*)wbf;
#pragma unroll
    for (int i = 0; i < 16; ++i) {
      int chunk = i * 256 + tid;       // 16B chunks: col = chunk>>5, slot = chunk&31
      uint4 v = src[chunk];
      int col = chunk >> 5, s = chunk & 31;
      int sp = s ^ (col & 31);
      *(uint4*)&wlds[col * 256 + sp * 8] = v;
    }
  }
  int w = tid >> 6, l = tid & 63;
  int lr = l & 31, g = l >> 5;
  int row = blockIdx.x * 64 + (w & 1) * 32 + lr;
  int c0 = (w >> 1) * 64;
  bool valid = row < M;
  const float* xrow = x + (size_t)row * 256;
  f32x16 acc0 = {}, acc1 = {};
  __syncthreads();
#pragma unroll
  for (int kt = 0; kt < 16; ++kt) {
    int k0 = kt * 16 + g * 8;          // lane's 8 contiguous k
    float4 f0 = make_float4(0.f, 0.f, 0.f, 0.f), f1 = f0;
    if (valid) {
      f0 = *(const float4*)(xrow + k0);
      f1 = *(const float4*)(xrow + k0 + 4);
    }
    short8v a;
    a[0] = (short)f2bf(f0.x); a[1] = (short)f2bf(f0.y);
    a[2] = (short)f2bf(f0.z); a[3] = (short)f2bf(f0.w);
    a[4] = (short)f2bf(f1.x); a[5] = (short)f2bf(f1.y);
    a[6] = (short)f2bf(f1.z); a[7] = (short)f2bf(f1.w);
    int sp = (kt * 2 + g) ^ lr;        // swizzled 16B slot
    short8v b0 = *(short8v*)&wlds[(c0 + lr) * 256 + sp * 8];
    short8v b1 = *(short8v*)&wlds[(c0 + 32 + lr) * 256 + sp * 8];
    acc0 = __builtin_amdgcn_mfma_f32_32x32x16_bf16(a, b0, acc0, 0, 0, 0);
    acc1 = __builtin_amdgcn_mfma_f32_32x32x16_bf16(a, b1, acc1, 0, 0, 0);
  }
  int j = lr + (w >> 1) * 32;          // hu pair index
  int p = c0 + lr;                     // actual feature col of tile0
  float bl = bias[p], bh = bias[p + 32];
#pragma unroll
  for (int r = 0; r < 16; ++r) {
    int mrow = blockIdx.x * 64 + (w & 1) * 32 + (r & 3) + 8 * (r >> 2) + 4 * g;
    if (mrow < M) {
      float di = dis[mrow];
      hu[(size_t)mrow * 64 + j] = pack_bf16(di * (acc0[r] + bl), di * (acc1[r] + bh));
    }
  }
}

// ---- aggregation: wave per node, register accumulate; out[i] = dis[i]*(sum+self) ----
// lane j holds feat pair (p, p+32), p = (j&31) | ((j&32)<<1).
__launch_bounds__(256)
__global__ void k_aggregate(const uint32_t* __restrict__ hu, const float* __restrict__ dis,
                            const int* __restrict__ offs, const int* __restrict__ csr,
                            float* __restrict__ out, int N, int E) {
  int wid = blockIdx.x * 4 + (threadIdx.x >> 6);
  int lane = threadIdx.x & 63;
  if (wid >= N) return;
  uint32_t ps = hu[(size_t)wid * 64 + lane];
  float ax = bf_lo(ps);   // self loop: hu' already has dis folded in
  float ay = bf_hi(ps);
  int e = offs[wid];
  int end = (wid + 1 < N) ? offs[wid + 1] : E;
  for (; e + 3 < end; e += 4) {
    int c0 = csr[e], c1 = csr[e + 1], c2 = csr[e + 2], c3 = csr[e + 3];
    uint32_t p0 = hu[(size_t)c0 * 64 + lane];
    uint32_t p1 = hu[(size_t)c1 * 64 + lane];
    uint32_t p2 = hu[(size_t)c2 * 64 + lane];
    uint32_t p3 = hu[(size_t)c3 * 64 + lane];
    ax += bf_lo(p0) + bf_lo(p1) + bf_lo(p2) + bf_lo(p3);
    ay += bf_hi(p0) + bf_hi(p1) + bf_hi(p2) + bf_hi(p3);
  }
  for (; e < end; ++e) {
    int c = csr[e];
    uint32_t p = hu[(size_t)c * 64 + lane];
    ax += bf_lo(p);
    ay += bf_hi(p);
  }
  float di = dis[wid];
  int p = (lane & 31) | ((lane & 32) << 1);
  out[(size_t)wid * 128 + p] = di * ax;
  out[(size_t)wid * 128 + p + 32] = di * ay;
}

// ---- fallback path (small workspace): count -> dis -> per-edge atomics ----
__global__ void k_count(const int* __restrict__ rows, int E, int* __restrict__ deg) {
  int e = blockIdx.x * blockDim.x + threadIdx.x;
  if (e < E) atomicAdd(&deg[rows[e]], 1);
}

__global__ void k_dis(const int* __restrict__ deg, float* __restrict__ dis, int N) {
  int i = blockIdx.x * blockDim.x + threadIdx.x;
  if (i < N) dis[i] = rsqrtf((float)(deg[i] + 1));
}

__launch_bounds__(256)
__global__ void k_selfinit(const uint32_t* __restrict__ hu, const float* __restrict__ dis,
                           float* __restrict__ out, int N) {
  int wid = blockIdx.x * 4 + (threadIdx.x >> 6);
  int lane = threadIdx.x & 63;
  if (wid >= N) return;
  float di = dis[wid];
  uint32_t p = hu[(size_t)wid * 64 + lane];
  int pc = (lane & 31) | ((lane & 32) << 1);
  out[(size_t)wid * 128 + pc] = di * bf_lo(p);
  out[(size_t)wid * 128 + pc + 32] = di * bf_hi(p);
}

__launch_bounds__(256)
__global__ void k_edge_atomic(const int* __restrict__ rows, const int* __restrict__ cols, int E,
                              const uint32_t* __restrict__ hu, const float* __restrict__ dis,
                              float* __restrict__ out) {
  int wid = blockIdx.x * 4 + (threadIdx.x >> 6);
  int lane = threadIdx.x & 63;
  if (wid >= E) return;
  int r = rows[wid], c = cols[wid];
  float w = dis[r];  // hu'[c] already carries dis[c]
  uint32_t p = hu[(size_t)c * 64 + lane];
  int pc = (lane & 31) | ((lane & 32) << 1);
  atomicAdd(&out[(size_t)r * 128 + pc], w * bf_lo(p));
  atomicAdd(&out[(size_t)r * 128 + pc + 32], w * bf_hi(p));
}

extern "C" void kernel_launch(void* const* d_in, const int* in_sizes, int n_in,
                              void* d_out, int out_size, void* d_ws, size_t ws_size,
                              hipStream_t stream) {
  const float* x    = (const float*)d_in[0];
  const int*   ei   = (const int*)d_in[1];
  const float* W    = (const float*)d_in[2];
  const float* bias = (const float*)d_in[3];
  float* out = (float*)d_out;

  const int N = in_sizes[0] / 256;   // 100000
  const int E = in_sizes[1] / 2;     // 3200000
  const int NB = (N + RB - 1) / RB;  // 196 buckets of 512 rows
  const int* rows = ei;
  const int* cols = ei + E;

  // workspace layout (256B aligned slices)
  size_t off = 0;
  auto alloc = [&](size_t bytes) -> void* {
    void* p = (char*)d_ws + off;
    off += (bytes + 255) & ~(size_t)255;
    return p;
  };
  uint32_t* hu    = (uint32_t*)alloc((size_t)N * 64 * 4);  // bf16-packed dis*h
  float*    dis   = (float*)alloc((size_t)N * 4);
  int*      deg   = (int*)alloc((size_t)N * 4);            // fallback only
  uint16_t* wbf   = (uint16_t*)alloc(32768 * 2);           // bf16 W, [col][k]
  int*      bcnt  = (int*)alloc((size_t)NBMAX * 4);
  int*      gbase = (int*)alloc((size_t)NBMAX * 4);
  int*      gcur  = (int*)alloc((size_t)NBMAX * 4);
  int*      offs  = (int*)alloc((size_t)N * 4);
  size_t small_end = off;
  uint32_t* temp  = (uint32_t*)alloc((size_t)E * 4);
  int*      csr   = (int*)alloc((size_t)E * 4);
  bool full = (off <= ws_size);
  bool atomic_ok = (small_end <= ws_size);

  k_wcast<<<128, 256, 0, stream>>>(W, wbf);

  if (full) {
    hipMemsetAsync(bcnt, 0, (size_t)NBMAX * 4, stream);
    k_bhist<<<512, 256, 0, stream>>>(rows, E, NB, bcnt);
    k_scanb<<<1, 1024, 0, stream>>>(bcnt, NB, gbase, gcur);
    k_part<<<(E + CHUNK - 1) / CHUNK, 1024, 0, stream>>>(rows, cols, E, NB, gcur, temp);
    k_csr_build<<<NB, 256, 0, stream>>>(gbase, bcnt, temp, N, offs, dis, csr);
    k_gemm<<<(N + 63) / 64, 256, 0, stream>>>(x, wbf, bias, dis, hu, N);
    k_aggregate<<<(N + 3) / 4, 256, 0, stream>>>(hu, dis, offs, csr, out, N, E);
  } else if (atomic_ok) {
    hipMemsetAsync(deg, 0, (size_t)N * 4, stream);
    k_count<<<(E + 255) / 256, 256, 0, stream>>>(rows, E, deg);
    k_dis<<<(N + 255) / 256, 256, 0, stream>>>(deg, dis, N);
    k_gemm<<<(N + 63) / 64, 256, 0, stream>>>(x, wbf, bias, dis, hu, N);
    k_selfinit<<<(N + 3) / 4, 256, 0, stream>>>(hu, dis, out, N);
    k_edge_atomic<<<(E + 3) / 4, 256, 0, stream>>>(rows, cols, E, hu, dis, out);
  }
}